// Round 9
// baseline (221.590 us; speedup 1.0000x reference)
//
#include <hip/hip_runtime.h>

typedef float f4 __attribute__((ext_vector_type(4)));

#define TT 256
#define KK 64
#define LOG2E 1.44269504f
#define LN2 0.69314718f
#define RL 32
#define RSTR 65          // ring line stride in uint2
#define DEADD (1 << 28)

struct DPS {
  float E1, E2, E3, E4, dgE;
  int d1, d2, d3, d4, dgd;
};

__device__ __forceinline__ float sumsq_fp8x4(unsigned int pk) {
  float d0 = __builtin_amdgcn_cvt_f32_fp8((int)pk, 0);
  float d1 = __builtin_amdgcn_cvt_f32_fp8((int)pk, 1);
  float d2 = __builtin_amdgcn_cvt_f32_fp8((int)pk, 2);
  float d3 = __builtin_amdgcn_cvt_f32_fp8((int)pk, 3);
  return (d0 * d0 + d1 * d1) + (d2 * d2 + d3 * d3);
}

// exp-domain DP cell, all full-rate VALU. value 2^-V = E * 2^-d, E in [0.5,1).
__device__ __forceinline__ void cellf(float& Eo, int& don,
                                      float EL, int dL, float ED, int dD,
                                      float EU, int dU, float m, int ci126) {
  int ref = min(min(dL, dD), dU);
  float S = ldexpf(EL, ref - dL) + ldexpf(ED, ref - dD) + ldexpf(EU, ref - dU);
  float v = m * S;                       // v in [0.25, 3)
  unsigned int u = __builtin_bit_cast(unsigned int, v);
  Eo = __builtin_bit_cast(float, (u & 0x007FFFFFu) | 0x3F000000u);
  don = (ref + ci126) - (int)(u >> 23);
}

// Two problems per wave (ILP doubling): fp8 MFMA cost tiles in anti-diagonal key order
// feed per-problem LDS rings; wave-synchronous exp-domain DP, 4 rows/lane.
__global__ __launch_bounds__(64)
void sdtw_dual(const float* __restrict__ X, const float* __restrict__ Y,
               float* __restrict__ out) {
  const int bid = blockIdx.x;          // 0..767
  const int t = threadIdx.x;
  const int hk = t >> 4, lr = t & 15;
  const int bpaddr = ((t + 63) & 63) << 2;

  __shared__ uint2 ring[2][RL * RSTR];   // .x fp8x4 mantissas m, .y u8x4 int costs ci
  __shared__ float saa[2][TT];           // 0.5*log2e*||q(A_r)||^2

  const float* Ap[2]; const float* Bp[2]; float wgt[2];
  #pragma unroll
  for (int pi = 0; pi < 2; ++pi) {
    int p = 2 * bid + pi;
    int type = p >> 9;                   // 0: xy, 1: xx, 2: yy
    int b = p & 511;
    Ap[pi] = (type == 2 ? Y : X) + (size_t)b * TT * KK;
    Bp[pi] = (type == 1 ? X : Y) + (size_t)b * TT * KK;
    wgt[pi] = (type == 0) ? (LN2 / 512.0f) : (-LN2 / 1024.0f);
  }

  // ---- zero-init rings (unwritten entries must decode as dead) ----
  #pragma unroll 4
  for (int i = 0; i < 33; ++i) {
    int idx = i * 64 + t;
    if (idx < RL * RSTR) {
      ring[0][idx] = make_uint2(0u, 0u);
      ring[1][idx] = make_uint2(0u, 0u);
    }
  }

  // ---- A fragments -> fp8 registers; quantized row norms -> saa (single wave: no barrier) ----
  uint2 af[2][16][2];
  #pragma unroll
  for (int pi = 0; pi < 2; ++pi) {
    #pragma unroll
    for (int Rt = 0; Rt < 16; ++Rt) {
      float nrm = 0.f;
      #pragma unroll
      for (int kk = 0; kk < 2; ++kk) {
        const float4* src = (const float4*)(Ap[pi] + (Rt * 16 + lr) * KK + kk * 32 + hk * 8);
        float4 x = src[0], y = src[1];
        unsigned int p0 = __builtin_amdgcn_cvt_pk_fp8_f32(x.x, x.y, 0, false);
        p0 = __builtin_amdgcn_cvt_pk_fp8_f32(x.z, x.w, p0, true);
        unsigned int p1 = __builtin_amdgcn_cvt_pk_fp8_f32(y.x, y.y, 0, false);
        p1 = __builtin_amdgcn_cvt_pk_fp8_f32(y.z, y.w, p1, true);
        af[pi][Rt][kk] = make_uint2(p0, p1);
        nrm += sumsq_fp8x4(p0) + sumsq_fp8x4(p1);
      }
      nrm += __shfl_xor(nrm, 16);
      nrm += __shfl_xor(nrm, 32);
      if (hk == 0) saa[pi][Rt * 16 + lr] = 0.5f * LOG2E * nrm;
    }
  }

  uint2 bwin[2][4][2];                   // sliding B-fragment window, slot = Ct & 3
  float bbR[2][4];                       // per-lane B-row norm for slot (== bbv needed later)

  DPS sa, sb;
  sa.E1 = sa.E2 = sa.E3 = sa.E4 = 0.f;
  sa.d1 = sa.d2 = sa.d3 = sa.d4 = DEADD;
  sa.dgE = (t == 0) ? 1.0f : 0.f;        // V[0][0] = 0 -> (E=1, d=0)
  sa.dgd = (t == 0) ? 0 : DEADD;
  sb = sa;

  auto step = [&](DPS& S, uint2 w) {
    float upE = __builtin_bit_cast(float,
        __builtin_amdgcn_ds_bpermute(bpaddr, __builtin_bit_cast(int, S.E4)));
    int upd = __builtin_amdgcn_ds_bpermute(bpaddr, S.d4);
    if (t == 0) { upE = 0.f; upd = DEADD; }
    float m0 = __builtin_amdgcn_cvt_f32_fp8((int)w.x, 0);
    float m1 = __builtin_amdgcn_cvt_f32_fp8((int)w.x, 1);
    float m2 = __builtin_amdgcn_cvt_f32_fp8((int)w.x, 2);
    float m3 = __builtin_amdgcn_cvt_f32_fp8((int)w.x, 3);
    int c0 = (int)(w.y & 255u) + 126;
    int c1 = (int)((w.y >> 8) & 255u) + 126;
    int c2 = (int)((w.y >> 16) & 255u) + 126;
    int c3 = (int)(w.y >> 24) + 126;
    float v1E, v2E, v3E, v4E; int v1d, v2d, v3d, v4d;
    cellf(v1E, v1d, S.E1, S.d1, S.dgE, S.dgd, upE, upd, m0, c0);
    cellf(v2E, v2d, S.E2, S.d2, S.E1, S.d1, v1E, v1d, m1, c1);
    cellf(v3E, v3d, S.E3, S.d3, S.E2, S.d2, v2E, v2d, m2, c2);
    cellf(v4E, v4d, S.E4, S.d4, S.E3, S.d3, v3E, v3d, m3, c3);
    S.E1 = v1E; S.d1 = v1d; S.E2 = v2E; S.d2 = v2d;
    S.E3 = v3E; S.d3 = v3d; S.E4 = v4E; S.d4 = v4d;
    S.dgE = upE; S.dgd = upd;
  };

  #pragma unroll 1
  for (int kbo = 0; kbo < 5; ++kbo) {
    #pragma unroll
    for (int q = 0; q < 4; ++q) {
      const int KB = kbo * 4 + q;        // runtime (wave-uniform guards below)
      // ---- load B fragment Ct=KB into slot q; norms stay in registers ----
      if (KB <= 15) {
        #pragma unroll
        for (int pi = 0; pi < 2; ++pi) {
          float nrm = 0.f;
          #pragma unroll
          for (int kk = 0; kk < 2; ++kk) {
            const float4* src = (const float4*)(Bp[pi] + (KB * 16 + lr) * KK + kk * 32 + hk * 8);
            float4 x = src[0], y = src[1];
            unsigned int p0 = __builtin_amdgcn_cvt_pk_fp8_f32(x.x, x.y, 0, false);
            p0 = __builtin_amdgcn_cvt_pk_fp8_f32(x.z, x.w, p0, true);
            unsigned int p1 = __builtin_amdgcn_cvt_pk_fp8_f32(y.x, y.y, 0, false);
            p1 = __builtin_amdgcn_cvt_pk_fp8_f32(y.z, y.w, p1, true);
            bwin[pi][q][kk] = make_uint2(p0, p1);
            nrm += sumsq_fp8x4(p0) + sumsq_fp8x4(p1);
          }
          nrm += __shfl_xor(nrm, 16);
          nrm += __shfl_xor(nrm, 32);
          bbR[pi][q] = 0.5f * LOG2E * nrm;   // every lane: norm of row KB*16+lr
        }
      }
      if (KB <= 18) {
        #pragma unroll
        for (int r = 0; r < 4; ++r) {
          const int k = KB * 4 + r;      // tile key = 4*Ct + Rt, 0..75
          // ---- produce tiles of key k: (Rt = r+4*dlt, Ct = KB-dlt), both problems ----
          #pragma unroll
          for (int dlt = 0; dlt < 4; ++dlt) {
            if (dlt <= KB && dlt >= KB - 15) {
              const int Rt = r + 4 * dlt;          // compile-time
              const int slot = (q - dlt) & 3;      // compile-time
              const int Ct = KB - dlt;
              #pragma unroll
              for (int pi = 0; pi < 2; ++pi) {
                f4 acc = {0.f, 0.f, 0.f, 0.f};
                acc = __builtin_amdgcn_mfma_f32_16x16x32_fp8_fp8(
                        __builtin_bit_cast(long, af[pi][Rt][0]),
                        __builtin_bit_cast(long, bwin[pi][slot][0]), acc, 0, 0, 0);
                acc = __builtin_amdgcn_mfma_f32_16x16x32_fp8_fp8(
                        __builtin_bit_cast(long, af[pi][Rt][1]),
                        __builtin_bit_cast(long, bwin[pi][slot][1]), acc, 0, 0, 0);
                f4 aav = *(const f4*)&saa[pi][Rt * 16 + hk * 4];
                float bbv = bbR[pi][slot];
                float c0 = fminf(fmaxf(fmaf(-LOG2E, acc.x, aav.x + bbv), 0.f), 254.0f);
                float c1 = fminf(fmaxf(fmaf(-LOG2E, acc.y, aav.y + bbv), 0.f), 254.0f);
                float c2 = fminf(fmaxf(fmaf(-LOG2E, acc.z, aav.z + bbv), 0.f), 254.0f);
                float c3 = fminf(fmaxf(fmaf(-LOG2E, acc.w, aav.w + bbv), 0.f), 254.0f);
                float f0 = truncf(c0), f1 = truncf(c1), f2 = truncf(c2), f3 = truncf(c3);
                float x0 = c0 - f0, x1 = c1 - f1, x2 = c2 - f2, x3 = c3 - f3;
                // m = 2^-x, x in [0,1): quadratic, err < 0.2%
                float m0 = fmaf(x0, fmaf(x0, 0.17157f, -0.67157f), 1.0f);
                float m1 = fmaf(x1, fmaf(x1, 0.17157f, -0.67157f), 1.0f);
                float m2 = fmaf(x2, fmaf(x2, 0.17157f, -0.67157f), 1.0f);
                float m3 = fmaf(x3, fmaf(x3, 0.17157f, -0.67157f), 1.0f);
                int pkm = __builtin_amdgcn_cvt_pk_fp8_f32(m0, m1, 0, false);
                pkm = __builtin_amdgcn_cvt_pk_fp8_f32(m2, m3, pkm, true);
                unsigned int pkc = (unsigned int)f0 | ((unsigned int)f1 << 8)
                                 | ((unsigned int)f2 << 16) | ((unsigned int)f3 << 24);
                const int t_row = 4 * Rt + hk;
                const int s1 = Ct * 16 + lr + t_row;     // diagonal line index
                ring[pi][(s1 & 31) * RSTR + t_row] = make_uint2((unsigned int)pkm, pkc);
              }
            }
          }
          // ---- 4 DP steps: lines 4k..4k+3 complete; interleave the two problems ----
          uint2 ca[4], cb[4];
          #pragma unroll
          for (int u = 0; u < 4; ++u) {
            const int ridx = ((4 * k + u) & 31) * RSTR + t;
            ca[u] = ring[0][ridx];
            cb[u] = ring[1][ridx];
          }
          step(sa, ca[0]); step(sb, cb[0]);
          step(sa, ca[1]); step(sb, cb[1]);
          step(sa, ca[2]); step(sb, cb[2]);
          step(sa, ca[3]); step(sb, cb[3]);
        }
      }
    }
  }

  // ---- tail: lines 304..318 ----
  #pragma unroll
  for (int u = 0; u < 15; ++u) {
    const int ridx = ((304 + u) & 31) * RSTR + t;
    uint2 wa = ring[0][ridx];
    uint2 wb = ring[1][ridx];
    step(sa, wa); step(sb, wb);
  }

  if (t == 63) {
    float V0 = (float)sa.d4 - __log2f(sa.E4);
    float V1 = (float)sb.d4 - __log2f(sb.E4);
    atomicAdd(out, wgt[0] * V0 + wgt[1] * V1);
  }
}

extern "C" void kernel_launch(void* const* d_in, const int* in_sizes, int n_in,
                              void* d_out, int out_size, void* d_ws, size_t ws_size,
                              hipStream_t stream) {
  const float* X = (const float*)d_in[0];
  const float* Y = (const float*)d_in[1];
  float* out = (float*)d_out;
  hipMemsetAsync(out, 0, sizeof(float) * out_size, stream);
  sdtw_dual<<<768, 64, 0, stream>>>(X, Y, out);
}

// Round 11
// 178.209 us; speedup vs baseline: 1.2434x; 1.2434x over previous
//
#include <hip/hip_runtime.h>

typedef _Float16 h2 __attribute__((ext_vector_type(2)));
typedef float f4 __attribute__((ext_vector_type(4)));

#define TT 256
#define KK 64
#define BIGV 1e10f
#define LOG2E 1.44269504f
#define LN2 0.69314718f
#define RL 32
#define RSTR 65

// softmin in log2-scaled domain (values pre-scaled by log2e): exact correspondence.
__device__ __forceinline__ float softmin3b(float a, float b, float c) {
  float m, d, M;
  asm("v_min3_f32 %0, %1, %2, %3" : "=v"(m) : "v"(a), "v"(b), "v"(c));
  asm("v_max3_f32 %0, %1, %2, %3" : "=v"(M) : "v"(a), "v"(b), "v"(c));
  asm("v_med3_f32 %0, %1, %2, %3" : "=v"(d) : "v"(a), "v"(b), "v"(c));
  float s = 1.0f + __builtin_amdgcn_exp2f(m - d) + __builtin_amdgcn_exp2f(m - M);
  return m - __log2f(s);
}

__device__ __forceinline__ float sumsq_fp8x4(unsigned int pk) {
  float d0 = __builtin_amdgcn_cvt_f32_fp8((int)pk, 0);
  float d1 = __builtin_amdgcn_cvt_f32_fp8((int)pk, 1);
  float d2 = __builtin_amdgcn_cvt_f32_fp8((int)pk, 2);
  float d3 = __builtin_amdgcn_cvt_f32_fp8((int)pk, 3);
  return (d0 * d0 + d1 * d1) + (d2 * d2 + d3 * d3);
}

// 2 waves per problem: wave0 = producer (fp8 MFMA cost tiles -> f16 LDS ring),
// wave1 = consumer (wave-synchronous softmin DP, 4 rows/lane). One barrier per key;
// producer runs one key ahead of the consumer.
__global__ __launch_bounds__(128)
void sdtw_pc(const float* __restrict__ X, const float* __restrict__ Y,
             float* __restrict__ out) {
  const int p = blockIdx.x;
  const int type = p >> 9;            // 0: xy, 1: xx, 2: yy
  const int b = p & 511;
  const float* Ap = (type == 2 ? Y : X) + (size_t)b * TT * KK;
  const float* Bp = (type == 1 ? X : Y) + (size_t)b * TT * KK;
  const float wgt = (type == 0) ? (LN2 / 512.0f) : (-LN2 / 1024.0f);

  __shared__ unsigned int ring0[RL * RSTR];   // f16x2 costs rows 4t+1,4t+2 (log2-units)
  __shared__ unsigned int ring1[RL * RSTR];   // f16x2 costs rows 4t+3,4t+4
  __shared__ float saa[TT];                   // 0.5*log2e*||q(A_r)||^2

  const int tid = threadIdx.x;
  const int wv = tid >> 6;            // 0 = producer wave, 1 = consumer wave
  const int t = tid & 63;
  const int hk = t >> 4, lr = t & 15;

  // ---- zero-init ring (unwritten entries read as cost 0; BIG+0 stays BIG) ----
  #pragma unroll
  for (int i = 0; i < 17; ++i) {
    int idx = i * 128 + tid;
    if (idx < RL * RSTR) { ring0[idx] = 0u; ring1[idx] = 0u; }
  }

  // producer-only register state (consumer lanes leave undef/unused)
  uint2 af[16][2];
  uint2 bwin[4][2];
  float bbR[4];

  if (wv == 0) {
    // ---- A fragments -> fp8 registers; quantized row norms -> saa ----
    #pragma unroll
    for (int Rt = 0; Rt < 16; ++Rt) {
      float nrm = 0.f;
      #pragma unroll
      for (int kk = 0; kk < 2; ++kk) {
        const float4* src = (const float4*)(Ap + (Rt * 16 + lr) * KK + kk * 32 + hk * 8);
        float4 x = src[0], y = src[1];
        unsigned int p0 = __builtin_amdgcn_cvt_pk_fp8_f32(x.x, x.y, 0, false);
        p0 = __builtin_amdgcn_cvt_pk_fp8_f32(x.z, x.w, p0, true);
        unsigned int p1 = __builtin_amdgcn_cvt_pk_fp8_f32(y.x, y.y, 0, false);
        p1 = __builtin_amdgcn_cvt_pk_fp8_f32(y.z, y.w, p1, true);
        af[Rt][kk] = make_uint2(p0, p1);
        nrm += sumsq_fp8x4(p0) + sumsq_fp8x4(p1);
      }
      nrm += __shfl_xor(nrm, 16);
      nrm += __shfl_xor(nrm, 32);
      if (hk == 0) saa[Rt * 16 + lr] = 0.5f * LOG2E * nrm;
    }
  }

  // consumer DP state (log2 domain, R5-verified)
  float vL1 = BIGV, vL2 = BIGV, vL3 = BIGV, vL4 = BIGV;
  float dg = (t == 0) ? 0.0f : BIGV;

  __syncthreads();

  #pragma unroll 1
  for (int kbo = 0; kbo < 5; ++kbo) {
    #pragma unroll
    for (int q = 0; q < 4; ++q) {
      const int KB = kbo * 4 + q;     // wave-uniform runtime
      // ---- producer: load B block Ct=KB into slot q; norm stays in registers ----
      if (wv == 0 && KB <= 15) {
        float nrm = 0.f;
        #pragma unroll
        for (int kk = 0; kk < 2; ++kk) {
          const float4* src = (const float4*)(Bp + (KB * 16 + lr) * KK + kk * 32 + hk * 8);
          float4 x = src[0], y = src[1];
          unsigned int p0 = __builtin_amdgcn_cvt_pk_fp8_f32(x.x, x.y, 0, false);
          p0 = __builtin_amdgcn_cvt_pk_fp8_f32(x.z, x.w, p0, true);
          unsigned int p1 = __builtin_amdgcn_cvt_pk_fp8_f32(y.x, y.y, 0, false);
          p1 = __builtin_amdgcn_cvt_pk_fp8_f32(y.z, y.w, p1, true);
          bwin[q][kk] = make_uint2(p0, p1);
          nrm += sumsq_fp8x4(p0) + sumsq_fp8x4(p1);
        }
        nrm += __shfl_xor(nrm, 16);
        nrm += __shfl_xor(nrm, 32);
        bbR[q] = 0.5f * LOG2E * nrm;  // every lane: norm of B row KB*16+lr
      }
      #pragma unroll
      for (int r = 0; r < 4; ++r) {
        const int k = KB * 4 + r;     // key index this iteration produces
        if (wv == 0) {
          if (KB <= 18) {
            // ---- produce tiles of key k: (Rt = r+4*dlt, Ct = KB-dlt) ----
            #pragma unroll
            for (int dlt = 0; dlt < 4; ++dlt) {
              if (dlt <= KB && KB - dlt <= 15) {       // wave-uniform
                const int Rt = r + 4 * dlt;            // compile-time
                const int slot = (q - dlt) & 3;        // compile-time
                const int Ct = KB - dlt;
                f4 acc = {0.f, 0.f, 0.f, 0.f};
                acc = __builtin_amdgcn_mfma_f32_16x16x32_fp8_fp8(
                        __builtin_bit_cast(long, af[Rt][0]),
                        __builtin_bit_cast(long, bwin[slot][0]), acc, 0, 0, 0);
                acc = __builtin_amdgcn_mfma_f32_16x16x32_fp8_fp8(
                        __builtin_bit_cast(long, af[Rt][1]),
                        __builtin_bit_cast(long, bwin[slot][1]), acc, 0, 0, 0);
                f4 aav = *(const f4*)&saa[Rt * 16 + hk * 4];
                float bbv = bbR[slot];
                float c0 = fmaf(-LOG2E, acc.x, aav.x + bbv);
                float c1 = fmaf(-LOG2E, acc.y, aav.y + bbv);
                float c2 = fmaf(-LOG2E, acc.z, aav.z + bbv);
                float c3 = fmaf(-LOG2E, acc.w, aav.w + bbv);
                unsigned int pk01 = __builtin_bit_cast(unsigned int,
                    __builtin_amdgcn_cvt_pkrtz(c0, c1));
                unsigned int pk23 = __builtin_bit_cast(unsigned int,
                    __builtin_amdgcn_cvt_pkrtz(c2, c3));
                const int t_row = 4 * Rt + hk;
                const int s1 = Ct * 16 + lr + t_row;   // skewed column line index
                const int widx = (s1 & 31) * RSTR + t_row;
                ring0[widx] = pk01;
                ring1[widx] = pk23;
              }
            }
          }
        } else {
          // ---- consumer: eat key k-1 (lines 4(k-1)..4(k-1)+3) ----
          const int kc = k - 1;
          if (kc >= 0 && kc <= 75) {
            unsigned int w0[4], w1[4];
            #pragma unroll
            for (int u = 0; u < 4; ++u) {
              const int ridx = ((4 * kc + u) & 31) * RSTR + t;
              w0[u] = ring0[ridx];
              w1[u] = ring1[ridx];
            }
            #pragma unroll
            for (int u = 0; u < 4; ++u) {
              float up1 = __shfl_up(vL4, 1);
              if (t == 0) up1 = BIGV;
              h2 cA = __builtin_bit_cast(h2, w0[u]);
              h2 cB = __builtin_bit_cast(h2, w1[u]);
              float v1 = (float)cA[0] + softmin3b(vL1, dg, up1);
              float v2 = (float)cA[1] + softmin3b(vL2, vL1, v1);
              float v3 = (float)cB[0] + softmin3b(vL3, vL2, v2);
              float v4 = (float)cB[1] + softmin3b(vL4, vL3, v3);
              vL1 = v1; vL2 = v2; vL3 = v3; vL4 = v4; dg = up1;
            }
          }
        }
        __syncthreads();
      }
    }
  }

  // ---- consumer tail: lines 304..318 (all keys produced; last barrier covers) ----
  if (wv == 1) {
    #pragma unroll
    for (int u = 0; u < 15; ++u) {
      const int ridx = ((304 + u) & 31) * RSTR + t;
      unsigned int a0 = ring0[ridx];
      unsigned int a1 = ring1[ridx];
      float up1 = __shfl_up(vL4, 1);
      if (t == 0) up1 = BIGV;
      h2 cA = __builtin_bit_cast(h2, a0);
      h2 cB = __builtin_bit_cast(h2, a1);
      float v1 = (float)cA[0] + softmin3b(vL1, dg, up1);
      float v2 = (float)cA[1] + softmin3b(vL2, vL1, v1);
      float v3 = (float)cB[0] + softmin3b(vL3, vL2, v2);
      float v4 = (float)cB[1] + softmin3b(vL4, vL3, v3);
      vL1 = v1; vL2 = v2; vL3 = v3; vL4 = v4; dg = up1;
    }
    // lane 63 holds V[256][256] (log2 domain)
    if (t == 63) atomicAdd(out, wgt * vL4);
  }
}

extern "C" void kernel_launch(void* const* d_in, const int* in_sizes, int n_in,
                              void* d_out, int out_size, void* d_ws, size_t ws_size,
                              hipStream_t stream) {
  const float* X = (const float*)d_in[0];
  const float* Y = (const float*)d_in[1];
  float* out = (float*)d_out;
  hipMemsetAsync(out, 0, sizeof(float) * out_size, stream);
  sdtw_pc<<<1536, 128, 0, stream>>>(X, Y, out);
}

// Round 12
// 160.871 us; speedup vs baseline: 1.3774x; 1.1078x over previous
//
#include <hip/hip_runtime.h>

typedef float f4 __attribute__((ext_vector_type(4)));

#define BIGV 1e10f
#define LOG2E 1.44269504f
#define LN2 0.69314718f
#define RSTR 66   // ring line stride in u32: read bank=(2L+t)&31 -> 2-way; writes <=2-way

// softmin in log2-scaled domain (values pre-scaled by log2e): exact correspondence.
__device__ __forceinline__ float softmin3b(float a, float b, float c) {
  float m, d, M;
  asm("v_min3_f32 %0, %1, %2, %3" : "=v"(m) : "v"(a), "v"(b), "v"(c));
  asm("v_max3_f32 %0, %1, %2, %3" : "=v"(M) : "v"(a), "v"(b), "v"(c));
  asm("v_med3_f32 %0, %1, %2, %3" : "=v"(d) : "v"(a), "v"(b), "v"(c));
  float s = 1.0f + __builtin_amdgcn_exp2f(m - d) + __builtin_amdgcn_exp2f(m - M);
  return m - __log2f(s);
}

__device__ __forceinline__ float sumsq_fp8x4(unsigned int pk) {
  float d0 = __builtin_amdgcn_cvt_f32_fp8((int)pk, 0);
  float d1 = __builtin_amdgcn_cvt_f32_fp8((int)pk, 1);
  float d2 = __builtin_amdgcn_cvt_f32_fp8((int)pk, 2);
  float d3 = __builtin_amdgcn_cvt_f32_fp8((int)pk, 3);
  return (d0 * d0 + d1 * d1) + (d2 * d2 + d3 * d3);
}

// One wave per problem, R5 schedule (produce key k+1 while consuming key k) with a
// COMPACT runtime key loop (I$-resident body). fp8 MFMA, fp8 single-ring costs.
__global__ __launch_bounds__(64)
void sdtw_c(const float* __restrict__ X, const float* __restrict__ Y,
            float* __restrict__ out) {
  const int p = blockIdx.x;
  const int type = p >> 9;            // 0: xy, 1: xx, 2: yy
  const int b = p & 511;
  const float* Ap = (type == 2 ? Y : X) + (size_t)b * 256 * 64;
  const float* Bp = (type == 1 ? X : Y) + (size_t)b * 256 * 64;
  const float wgt = (type == 0) ? (LN2 / 512.0f) : (-LN2 / 1024.0f);

  __shared__ unsigned int ring[32 * RSTR];  // fp8x4 costs per (line, row-quad)  8448 B
  __shared__ unsigned int sB[4096];         // fp8 B rows, swizzled              16384 B
  __shared__ _Float16 saa[256];             // 0.5*log2e*||q(A_r)||^2 (f16)        512 B
  __shared__ _Float16 sbb[256];             //                                     512 B

  const int t = threadIdx.x;
  const int hk = t >> 4, lr = t & 15;

  // ---- zero-init ring (avoid NaN-pattern fp8 decode from uninitialized LDS) ----
  #pragma unroll 1
  for (int i = 0; i < 33; ++i) {
    int idx = i * 64 + t;
    if (idx < 32 * RSTR) ring[idx] = 0u;
  }

  // ---- stage B -> fp8 LDS (swizzled) + quantized row norms (runtime loop) ----
  {
    const float4* B4 = (const float4*)Bp;
    const int q = t & 15;
    #pragma unroll 1
    for (int it = 0; it < 64; ++it) {
      int pidx = it * 64 + t;          // float4 index, lane-consecutive
      int row = pidx >> 4;
      float4 v = B4[pidx];
      unsigned int pk = __builtin_amdgcn_cvt_pk_fp8_f32(v.x, v.y, 0, false);
      pk = __builtin_amdgcn_cvt_pk_fp8_f32(v.z, v.w, pk, true);
      sB[row * 16 + (q ^ ((row & 7) << 1))] = pk;
      float pr = sumsq_fp8x4(pk);
      pr += __shfl_xor(pr, 1);
      pr += __shfl_xor(pr, 2);
      pr += __shfl_xor(pr, 4);
      pr += __shfl_xor(pr, 8);
      if (q == 0) sbb[row] = (_Float16)(0.5f * LOG2E * pr);
    }
  }

  // ---- A fragments -> fp8 registers (64 VGPR) + quantized row norms ----
  uint2 af[16][2];
  #pragma unroll
  for (int Rt = 0; Rt < 16; ++Rt) {
    float nrm = 0.f;
    #pragma unroll
    for (int kk = 0; kk < 2; ++kk) {
      const float4* src = (const float4*)(Ap + (Rt * 16 + lr) * 64 + kk * 32 + hk * 8);
      float4 x = src[0], y = src[1];
      unsigned int p0 = __builtin_amdgcn_cvt_pk_fp8_f32(x.x, x.y, 0, false);
      p0 = __builtin_amdgcn_cvt_pk_fp8_f32(x.z, x.w, p0, true);
      unsigned int p1 = __builtin_amdgcn_cvt_pk_fp8_f32(y.x, y.y, 0, false);
      p1 = __builtin_amdgcn_cvt_pk_fp8_f32(y.z, y.w, p1, true);
      af[Rt][kk] = make_uint2(p0, p1);
      nrm += sumsq_fp8x4(p0) + sumsq_fp8x4(p1);
    }
    nrm += __shfl_xor(nrm, 16);
    nrm += __shfl_xor(nrm, 32);
    if (hk == 0) saa[Rt * 16 + lr] = (_Float16)(0.5f * LOG2E * nrm);
  }

  // ---- DP state (log2 domain, R5-verified) ----
  float vL1 = BIGV, vL2 = BIGV, vL3 = BIGV, vL4 = BIGV;
  float dg = (t == 0) ? 0.0f : BIGV;

  // ---- produce one tile: Rt compile-time, Ct runtime ----
  #define PRODUCE_TILE(RT, CT)                                                     \
    {                                                                              \
      int n_ = (CT) * 16 + lr;                                                     \
      int sw_ = n_ & 7;                                                            \
      uint2 b0_ = *(const uint2*)&sB[n_ * 16 + 2 * (hk ^ sw_)];                    \
      uint2 b1_ = *(const uint2*)&sB[n_ * 16 + 2 * ((hk + 4) ^ sw_)];              \
      f4 acc_ = {0.f, 0.f, 0.f, 0.f};                                              \
      acc_ = __builtin_amdgcn_mfma_f32_16x16x32_fp8_fp8(                           \
               __builtin_bit_cast(long, af[RT][0]), __builtin_bit_cast(long, b0_), \
               acc_, 0, 0, 0);                                                     \
      acc_ = __builtin_amdgcn_mfma_f32_16x16x32_fp8_fp8(                           \
               __builtin_bit_cast(long, af[RT][1]), __builtin_bit_cast(long, b1_), \
               acc_, 0, 0, 0);                                                     \
      int r0_ = (RT) * 16 + hk * 4;                                                \
      float bbv_ = (float)sbb[n_];                                                 \
      float c0_ = fmaf(-LOG2E, acc_.x, (float)saa[r0_ + 0] + bbv_);                \
      float c1_ = fmaf(-LOG2E, acc_.y, (float)saa[r0_ + 1] + bbv_);                \
      float c2_ = fmaf(-LOG2E, acc_.z, (float)saa[r0_ + 2] + bbv_);                \
      float c3_ = fmaf(-LOG2E, acc_.w, (float)saa[r0_ + 3] + bbv_);                \
      int pk_ = __builtin_amdgcn_cvt_pk_fp8_f32(c0_, c1_, 0, false);               \
      pk_ = __builtin_amdgcn_cvt_pk_fp8_f32(c2_, c3_, pk_, true);                  \
      int tr_ = 4 * (RT) + hk;                                                     \
      int s1_ = n_ + tr_;                                                          \
      ring[(s1_ & 31) * RSTR + tr_] = (unsigned int)pk_;                           \
    }

  #define DP_STEP(CW)                                                              \
    {                                                                              \
      float up1 = __shfl_up(vL4, 1);                                               \
      if (t == 0) up1 = BIGV;                                                      \
      float c0 = __builtin_amdgcn_cvt_f32_fp8((int)(CW), 0);                       \
      float c1 = __builtin_amdgcn_cvt_f32_fp8((int)(CW), 1);                       \
      float c2 = __builtin_amdgcn_cvt_f32_fp8((int)(CW), 2);                       \
      float c3 = __builtin_amdgcn_cvt_f32_fp8((int)(CW), 3);                       \
      float v1 = c0 + softmin3b(vL1, dg, up1);                                     \
      float v2 = c1 + softmin3b(vL2, vL1, v1);                                     \
      float v3 = c2 + softmin3b(vL3, vL2, v2);                                     \
      float v4 = c3 + softmin3b(vL4, vL3, v3);                                     \
      vL1 = v1; vL2 = v2; vL3 = v3; vL4 = v4; dg = up1;                            \
    }

  // ---- produce key 0 (single tile Rt=0, Ct=0) ----
  PRODUCE_TILE(0, 0)

  // ---- main key loop: COMPACT body (runtime KB), r/dlt unrolled for static af ----
  #pragma unroll 1
  for (int KB = 0; KB < 19; ++KB) {
    #pragma unroll
    for (int r = 0; r < 4; ++r) {
      const int k = 4 * KB + r;       // consumed key, 0..75
      // prefetch this key's 4 lines
      unsigned int w0 = ring[((4 * k + 0) & 31) * RSTR + t];
      unsigned int w1 = ring[((4 * k + 1) & 31) * RSTR + t];
      unsigned int w2 = ring[((4 * k + 2) & 31) * RSTR + t];
      unsigned int w3 = ring[((4 * k + 3) & 31) * RSTR + t];
      // produce key k+1 (r' = (r+1)&3 is compile-time)
      if (k < 75) {
        const int KBp = KB + (r == 3 ? 1 : 0);
        #pragma unroll
        for (int dlt = 0; dlt < 4; ++dlt) {
          int Ct = KBp - dlt;
          if (Ct >= 0 && Ct <= 15) {  // wave-uniform runtime guard
            PRODUCE_TILE(((r + 1) & 3) + 4 * dlt, Ct)
          }
        }
      }
      DP_STEP(w0)
      DP_STEP(w1)
      DP_STEP(w2)
      DP_STEP(w3)
    }
  }

  // ---- tail: lines 304..318 (runtime loop) ----
  #pragma unroll 1
  for (int u = 0; u < 15; ++u) {
    unsigned int cw = ring[((304 + u) & 31) * RSTR + t];
    DP_STEP(cw)
  }

  // lane 63 holds V[256][256] (log2 domain)
  if (t == 63) atomicAdd(out, wgt * vL4);
}

extern "C" void kernel_launch(void* const* d_in, const int* in_sizes, int n_in,
                              void* d_out, int out_size, void* d_ws, size_t ws_size,
                              hipStream_t stream) {
  const float* X = (const float*)d_in[0];
  const float* Y = (const float*)d_in[1];
  float* out = (float*)d_out;
  hipMemsetAsync(out, 0, sizeof(float) * out_size, stream);
  sdtw_c<<<1536, 64, 0, stream>>>(X, Y, out);
}